// Round 9
// baseline (781.252 us; speedup 1.0000x reference)
//
#include <hip/hip_runtime.h>
#include <stdint.h>

#define BB 16
#define NN 4096
#define CC 64
#define NPOINT 1024
#define KK 32
#define F1 64
#define F2 64
#define F3 128

#define FPS_T 256          // FPS compute threads: 4 waves (1 per SIMD)
#define PPT (NN / FPS_T)   // 16 points per thread

// ---------------- DPP 64-lane max-reduce helpers ----------------
#if defined(__has_builtin)
#if __has_builtin(__builtin_amdgcn_update_dpp)
#define HAS_DPP 1
#endif
#endif

#ifdef HAS_DPP
template <int CTRL>
__device__ __forceinline__ unsigned long long dpp_move64(unsigned long long k) {
    int lo = __builtin_amdgcn_update_dpp(0, (int)(unsigned)k,         CTRL, 0xF, 0xF, false);
    int hi = __builtin_amdgcn_update_dpp(0, (int)(unsigned)(k >> 32), CTRL, 0xF, 0xF, false);
    return ((unsigned long long)(unsigned)hi << 32) | (unsigned)lo;
}
__device__ __forceinline__ unsigned long long wave_max_key(unsigned long long key) {
    unsigned long long o;
    o = dpp_move64<0x111>(key); if (o > key) key = o;   // row_shr:1
    o = dpp_move64<0x112>(key); if (o > key) key = o;   // row_shr:2
    o = dpp_move64<0x114>(key); if (o > key) key = o;   // row_shr:4
    o = dpp_move64<0x118>(key); if (o > key) key = o;   // row_shr:8
    o = dpp_move64<0x142>(key); if (o > key) key = o;   // row_bcast15
    o = dpp_move64<0x143>(key); if (o > key) key = o;   // row_bcast31 -> lane63 has max
    return key;
}
#else
__device__ __forceinline__ unsigned long long wave_max_key(unsigned long long key) {
#pragma unroll
    for (int off = 32; off > 0; off >>= 1) {
        unsigned long long o = __shfl_xor(key, off, 64);
        if (o > key) key = o;
    }
    return key;
}
#endif

// shared-memory arena (union of FPS and MLP layouts)
// FPS : xs[4096] ys[4096] zs[4096] (49152) | wred 2x4 u64 (64B) @49152
//       cbuf 2x24 f (192B) @49216 -> end 49408
// MLP : gbuf 32x68 (8704) @0 | hbuf 32x64 (8192) @8704 | pmax 8x128 (4096) @16896
//       cmask 64 u64 (512) @20992 | nbr 32 i (128) @21504
#define SMEM_BYTES 49664
#define WRED_OFF 49152
#define CBUF_OFF 49216

// amdgpu_waves_per_eu(2,2): pin the compiler's occupancy TARGET to 2 waves/EU
// -> 256-VGPR budget. History: R5/R7 (default heuristic) rematerialized
// px/py/pz from LDS (VGPR=52-60); R8 removed the LDS alias and it remat'd
// from GLOBAL instead (VGPR still 60, 48 L2 loads per serial iteration);
// R6's pins without the occupancy pin hit the heuristic's ~90-VGPR cap and
// SPILLED. Pins + explicit 2-wave target let the 64 floats of FPS state
// (px/py/pz/dist) finally live in registers with headroom, no spill.
// Occupancy cost: ~1 block/CU chip-wide; MLP consumer capacity at 1 block/CU
// (~60 blocks/us) still far exceeds FPS production (~23 blocks/us).
__global__ __launch_bounds__(512)
__attribute__((amdgpu_waves_per_eu(2, 2)))
void fused_kernel(const float* __restrict__ xyz,
                  const float* __restrict__ points,
                  const float* __restrict__ w0, const float* __restrict__ b0,
                  const float* __restrict__ w1, const float* __restrict__ b1,
                  const float* __restrict__ w2, const float* __restrict__ b2,
                  float* __restrict__ out_xyz,
                  float* __restrict__ out_points,
                  int* __restrict__ ctr) {
    __shared__ __align__(16) char smem[SMEM_BYTES];
    const int tid = threadIdx.x;

    if (blockIdx.x < BB) {
        // ================= FPS (blocks 0..15, resident first => no deadlock) ====
        asm volatile("s_setprio 3");
        float* xs = (float*)smem;
        float* ys = xs + NN;
        float* zs = ys + NN;
        unsigned long long (*wred)[4] = (unsigned long long (*)[4])(smem + WRED_OFF);
        float (*cbuf)[24] = (float (*)[24])(smem + CBUF_OFF);   // double-buffered

        const int b = blockIdx.x;
        const float* __restrict__ xb = xyz + (size_t)b * (NN * 3);
        float* xo = out_xyz + (size_t)b * NPOINT * 3;

        if (tid < FPS_T) {
            // -------- compute waves 0..3: register-resident points ------------
            float px[PPT], py[PPT], pz[PPT], dist[PPT];
#pragma unroll
            for (int t = 0; t < PPT; ++t) {
                int p = tid + t * FPS_T;
                px[t] = xb[p * 3 + 0];
                py[t] = xb[p * 3 + 1];
                pz[t] = xb[p * 3 + 2];
                // pin: loaded values become opaque -> compiler cannot
                // rematerialize them (from global OR LDS) inside the loop
                asm volatile("" : "+v"(px[t]), "+v"(py[t]), "+v"(pz[t]));
                dist[t] = 1e10f;
            }
            __syncthreads();             // publisher waves staged xs/ys/zs

            const int lane = tid & 63, wid = tid >> 6;   // wid 0..3
            float cx = xs[0], cy = ys[0], cz = zs[0];

            for (int i = 0; i < NPOINT; ++i) {
                if (tid == 0) {          // stage centroid i into LDS (cheap)
                    float* cb = cbuf[(i >> 3) & 1];
                    cb[(i & 7) * 3 + 0] = cx;
                    cb[(i & 7) * 3 + 1] = cy;
                    cb[(i & 7) * 3 + 2] = cz;
                }
                float bd = -1.0f; int bp = 0;
#pragma unroll
                for (int t = 0; t < PPT; ++t) {
                    float dx = __fsub_rn(px[t], cx);
                    float dy = __fsub_rn(py[t], cy);
                    float dz = __fsub_rn(pz[t], cz);
                    float d  = __fadd_rn(__fadd_rn(__fmul_rn(dx, dx), __fmul_rn(dy, dy)),
                                         __fmul_rn(dz, dz));
                    float nd = fminf(dist[t], d);
                    dist[t] = nd;
                    if (nd > bd) { bd = nd; bp = tid + t * FPS_T; }
                }
                unsigned long long key = (((unsigned long long)__float_as_uint(bd)) << 32)
                                       | (unsigned int)(NN - 1 - bp);
                key = wave_max_key(key);
                if (lane == 63) wred[i & 1][wid] = key;
                __syncthreads();

                unsigned long long best = wred[i & 1][0];
#pragma unroll
                for (int w = 1; w < 4; ++w) {
                    unsigned long long o = wred[i & 1][w];
                    if (o > best) best = o;
                }
                int bi = (NN - 1) - (int)(best & 0xffffffffu);
                cx = xs[bi]; cy = ys[bi]; cz = zs[bi];
            }
        } else {
            // -------- waves 4..7: stage LDS coords, then barrier-matched publish
            {
                const int q = tid - FPS_T;     // 0..255
#pragma unroll
                for (int t = 0; t < PPT; ++t) {
                    int p = q + t * FPS_T;
                    xs[p] = xb[p * 3 + 0];
                    ys[p] = xb[p * 3 + 1];
                    zs[p] = xb[p * 3 + 2];
                }
            }
            __syncthreads();             // matches compute's post-load barrier

            for (int i = 0; i < NPOINT; ++i) {
                __syncthreads();         // matches compute's mid-iter barrier
                if (tid == FPS_T && (i & 7) == 7) {
                    // Pipelined publish: vmcnt(0) -> previous group's stores are
                    // done -> bump ctr for it; then issue this group's stores.
                    asm volatile("s_waitcnt vmcnt(0)" ::: "memory");
                    if (i > 7)
                        __hip_atomic_store(&ctr[b * 16], i - 7,
                                           __ATOMIC_RELAXED, __HIP_MEMORY_SCOPE_AGENT);
                    const unsigned long long* cbu =
                        (const unsigned long long*)cbuf[(i >> 3) & 1];
                    unsigned long long* dst =
                        (unsigned long long*)(xo + (size_t)(i - 7) * 3);
#pragma unroll
                    for (int q = 0; q < 12; ++q)
                        __hip_atomic_store(dst + q, cbu[q],
                                           __ATOMIC_RELAXED, __HIP_MEMORY_SCOPE_AGENT);
                }
            }
            if (tid == FPS_T) {          // final drain: last two groups visible
                asm volatile("s_waitcnt vmcnt(0)" ::: "memory");
                __hip_atomic_store(&ctr[b * 16], NPOINT,
                                   __ATOMIC_RELAXED, __HIP_MEMORY_SCOPE_AGENT);
            }
        }
    } else {
        // ================= fused ball query + gather + MLP + maxpool ===========
        // (R0/R2/R5-proven consumer: 1 centroid/block, s-major, relaxed protocol)
        float (*gbuf)[68] = (float (*)[68])smem;                 // 32 x (67+pad)
        float (*hbuf)[F1] = (float (*)[F1])(smem + 8704);        // 32 x 64
        float (*pmax)[F3] = (float (*)[F3])(smem + 16896);       // 8 x 128
        unsigned long long* cmask = (unsigned long long*)(smem + 20992);
        int* nbr = (int*)(smem + 21504);

        const int gi = blockIdx.x - BB;
        const int s = gi >> 4;          // s-major: early blocks need early centroids
        const int b = gi & 15;
        const int g = b * NPOINT + s;
        const int f = tid & 63;
        const int wid = tid >> 6;       // 0..7

        // wait until centroid s is published. No ACQUIRE: producer data is
        // sc1/LLC-coherent and centroid reads below are sc1 relaxed-atomic
        // loads; __syncthreads orders the block. (no buffer_inv)
        if (tid == 0) {
            while (__hip_atomic_load(&ctr[b * 16], __ATOMIC_RELAXED,
                                     __HIP_MEMORY_SCOPE_AGENT) < s + 1)
                __builtin_amdgcn_s_sleep(2);
        }
        __syncthreads();

        // centroid via agent-scope loads (LLC-direct; immune to stale per-XCD L2)
        unsigned int ux = __hip_atomic_load((unsigned int*)&out_xyz[(size_t)g * 3 + 0],
                                            __ATOMIC_RELAXED, __HIP_MEMORY_SCOPE_AGENT);
        unsigned int uy = __hip_atomic_load((unsigned int*)&out_xyz[(size_t)g * 3 + 1],
                                            __ATOMIC_RELAXED, __HIP_MEMORY_SCOPE_AGENT);
        unsigned int uz = __hip_atomic_load((unsigned int*)&out_xyz[(size_t)g * 3 + 2],
                                            __ATOMIC_RELAXED, __HIP_MEMORY_SCOPE_AGENT);
        const float cx = __uint_as_float(ux);
        const float cy = __uint_as_float(uy);
        const float cz = __uint_as_float(uz);

        // ---- phase A1: 8 waves scan all 4096 points ----
        {
            const float* __restrict__ xb = xyz + (size_t)b * (NN * 3);
#pragma unroll
            for (int j = 0; j < 8; ++j) {
                int chunk = wid * 8 + j;
                int p = chunk * 64 + f;
                float x = xb[p * 3 + 0];
                float y = xb[p * 3 + 1];
                float z = xb[p * 3 + 2];
                float dx = __fsub_rn(cx, x);
                float dy = __fsub_rn(cy, y);
                float dz = __fsub_rn(cz, z);
                float d2 = __fadd_rn(__fadd_rn(__fmul_rn(dx, dx), __fmul_rn(dy, dy)),
                                     __fmul_rn(dz, dz));
                unsigned long long m = __ballot(d2 <= 0.04f);  // float32(0.2*0.2)
                if (f == 0) cmask[chunk] = m;
            }
        }
        __syncthreads();

        // ---- phase A2: wave 0 — ordered compaction of the 32 smallest indices ----
        if (tid < 64) {
            unsigned long long m = cmask[tid];
            int cnt = (int)__popcll(m);
            int v = cnt;
#pragma unroll
            for (int off = 1; off < 64; off <<= 1) {
                int u = __shfl_up(v, off, 64);
                if (tid >= off) v += u;
            }
            int excl = v - cnt;
            int total = __shfl(v, 63, 64);
            unsigned long long mm = m;
            int r = excl;
            while (mm && r < KK) {
                int bpos = __ffsll(mm) - 1;
                mm &= mm - 1;
                nbr[r++] = tid * 64 + bpos;
            }
            if (total < KK) {
                unsigned long long nz = __ballot(cnt > 0);
                int fchunk = __ffsll(nz) - 1;
                unsigned long long fm = cmask[fchunk];
                int first = fchunk * 64 + __ffsll(fm) - 1;
                if (tid >= total && tid < KK) nbr[tid] = first;
            }
        }
        __syncthreads();

        // ---- phase B: gather into LDS ----
        {
            const float* __restrict__ pb = points + (size_t)b * NN * CC;
#pragma unroll
            for (int m = 0; m < 4; ++m) {
                int k = wid + 8 * m;
                int idx = nbr[k] & (NN - 1);
                gbuf[k][f] = pb[(size_t)idx * CC + f];
            }
            if (tid < 96) {
                int k = tid & 31, q = tid >> 5;
                int idx = nbr[k] & (NN - 1);
                float v = xyz[((size_t)b * NN + idx) * 3 + q];
                float cq = (q == 0) ? cx : ((q == 1) ? cy : cz);
                gbuf[k][CC + q] = __fsub_rn(v, cq);
            }
        }
        __syncthreads();

        float acc[4];

        // ---- layer 1: 67 -> 64 ----
#pragma unroll
        for (int m = 0; m < 4; ++m) acc[m] = 0.0f;
#pragma unroll 4
        for (int c4 = 0; c4 < 64; c4 += 4) {
            float wv0 = w0[(c4 + 0) * F1 + f];
            float wv1 = w0[(c4 + 1) * F1 + f];
            float wv2 = w0[(c4 + 2) * F1 + f];
            float wv3 = w0[(c4 + 3) * F1 + f];
#pragma unroll
            for (int m = 0; m < 4; ++m) {
                float4 gv = *(const float4*)&gbuf[wid + 8 * m][c4];
                acc[m] = fmaf(gv.x, wv0, acc[m]);
                acc[m] = fmaf(gv.y, wv1, acc[m]);
                acc[m] = fmaf(gv.z, wv2, acc[m]);
                acc[m] = fmaf(gv.w, wv3, acc[m]);
            }
        }
        {
            float wv0 = w0[64 * F1 + f];
            float wv1 = w0[65 * F1 + f];
            float wv2 = w0[66 * F1 + f];
#pragma unroll
            for (int m = 0; m < 4; ++m) {
                int k = wid + 8 * m;
                acc[m] = fmaf(gbuf[k][64], wv0, acc[m]);
                acc[m] = fmaf(gbuf[k][65], wv1, acc[m]);
                acc[m] = fmaf(gbuf[k][66], wv2, acc[m]);
            }
        }
        {
            float bb = b0[f];
#pragma unroll
            for (int m = 0; m < 4; ++m)
                hbuf[wid + 8 * m][f] = fmaxf(acc[m] + bb, 0.0f);
        }
        __syncthreads();

        // ---- layer 2: 64 -> 64 ----
#pragma unroll
        for (int m = 0; m < 4; ++m) acc[m] = 0.0f;
#pragma unroll 4
        for (int c4 = 0; c4 < 64; c4 += 4) {
            float wv0 = w1[(c4 + 0) * F2 + f];
            float wv1 = w1[(c4 + 1) * F2 + f];
            float wv2 = w1[(c4 + 2) * F2 + f];
            float wv3 = w1[(c4 + 3) * F2 + f];
#pragma unroll
            for (int m = 0; m < 4; ++m) {
                float4 gv = *(const float4*)&hbuf[wid + 8 * m][c4];
                acc[m] = fmaf(gv.x, wv0, acc[m]);
                acc[m] = fmaf(gv.y, wv1, acc[m]);
                acc[m] = fmaf(gv.z, wv2, acc[m]);
                acc[m] = fmaf(gv.w, wv3, acc[m]);
            }
        }
        {
            float bb = b1[f];
#pragma unroll
            for (int m = 0; m < 4; ++m)
                gbuf[wid + 8 * m][f] = fmaxf(acc[m] + bb, 0.0f);
        }
        __syncthreads();

        // ---- layer 3: 64 -> 128 + maxpool ----
        float a0[4], a1[4];
#pragma unroll
        for (int m = 0; m < 4; ++m) { a0[m] = 0.0f; a1[m] = 0.0f; }
#pragma unroll 2
        for (int c4 = 0; c4 < 64; c4 += 4) {
            float w00 = w2[(c4 + 0) * F3 + f], w10 = w2[(c4 + 0) * F3 + f + 64];
            float w01 = w2[(c4 + 1) * F3 + f], w11 = w2[(c4 + 1) * F3 + f + 64];
            float w02 = w2[(c4 + 2) * F3 + f], w12 = w2[(c4 + 2) * F3 + f + 64];
            float w03 = w2[(c4 + 3) * F3 + f], w13 = w2[(c4 + 3) * F3 + f + 64];
#pragma unroll
            for (int m = 0; m < 4; ++m) {
                float4 gv = *(const float4*)&gbuf[wid + 8 * m][c4];
                a0[m] = fmaf(gv.x, w00, a0[m]);  a1[m] = fmaf(gv.x, w10, a1[m]);
                a0[m] = fmaf(gv.y, w01, a0[m]);  a1[m] = fmaf(gv.y, w11, a1[m]);
                a0[m] = fmaf(gv.z, w02, a0[m]);  a1[m] = fmaf(gv.z, w12, a1[m]);
                a0[m] = fmaf(gv.w, w03, a0[m]);  a1[m] = fmaf(gv.w, w13, a1[m]);
            }
        }
        {
            float pm0 = -1e30f, pm1 = -1e30f;
#pragma unroll
            for (int m = 0; m < 4; ++m) {
                pm0 = fmaxf(pm0, a0[m]);
                pm1 = fmaxf(pm1, a1[m]);
            }
            pmax[wid][f] = pm0;
            pmax[wid][f + 64] = pm1;
        }
        __syncthreads();
        if (tid < F3) {
            float v = pmax[0][tid];
#pragma unroll
            for (int w = 1; w < 8; ++w) v = fmaxf(v, pmax[w][tid]);
            v = fmaxf(v + b2[tid], 0.0f);   // relu(max+b) == max(relu(+b))
            out_points[(size_t)g * F3 + tid] = v;
        }
    }
}

extern "C" void kernel_launch(void* const* d_in, const int* in_sizes, int n_in,
                              void* d_out, int out_size, void* d_ws, size_t ws_size,
                              hipStream_t stream) {
    const float* xyz    = (const float*)d_in[0];
    const float* points = (const float*)d_in[1];
    const float* w0 = (const float*)d_in[2];
    const float* b0 = (const float*)d_in[3];
    const float* w1 = (const float*)d_in[4];
    const float* b1 = (const float*)d_in[5];
    const float* w2 = (const float*)d_in[6];
    const float* b2 = (const float*)d_in[7];

    float* out_xyz    = (float*)d_out;
    float* out_points = out_xyz + (size_t)BB * NPOINT * 3;
    int*   ctr        = (int*)d_ws;   // 16 counters, 64B stride (1 KiB used)

    fused_kernel<<<BB + BB * NPOINT, 512, 0, stream>>>(
        xyz, points, w0, b0, w1, b1, w2, b2, out_xyz, out_points, ctr);
}

// Round 10
// 751.060 us; speedup vs baseline: 1.0402x; 1.0402x over previous
//
#include <hip/hip_runtime.h>
#include <stdint.h>

#define BB 16
#define NN 4096
#define CC 64
#define NPOINT 1024
#define KK 32
#define F1 64
#define F2 64
#define F3 128

#define FPS_T 256          // FPS compute threads: 4 waves (1 per SIMD)
#define PPT (NN / FPS_T)   // 16 points per thread

// ---------------- DPP 64-lane max-reduce helpers ----------------
#if defined(__has_builtin)
#if __has_builtin(__builtin_amdgcn_update_dpp)
#define HAS_DPP 1
#endif
#endif

#ifdef HAS_DPP
template <int CTRL>
__device__ __forceinline__ unsigned long long dpp_move64(unsigned long long k) {
    int lo = __builtin_amdgcn_update_dpp(0, (int)(unsigned)k,         CTRL, 0xF, 0xF, false);
    int hi = __builtin_amdgcn_update_dpp(0, (int)(unsigned)(k >> 32), CTRL, 0xF, 0xF, false);
    return ((unsigned long long)(unsigned)hi << 32) | (unsigned)lo;
}
__device__ __forceinline__ unsigned long long wave_max_key(unsigned long long key) {
    unsigned long long o;
    o = dpp_move64<0x111>(key); if (o > key) key = o;   // row_shr:1
    o = dpp_move64<0x112>(key); if (o > key) key = o;   // row_shr:2
    o = dpp_move64<0x114>(key); if (o > key) key = o;   // row_shr:4
    o = dpp_move64<0x118>(key); if (o > key) key = o;   // row_shr:8
    o = dpp_move64<0x142>(key); if (o > key) key = o;   // row_bcast15
    o = dpp_move64<0x143>(key); if (o > key) key = o;   // row_bcast31 -> lane63 has max
    return key;
}
#else
__device__ __forceinline__ unsigned long long wave_max_key(unsigned long long key) {
#pragma unroll
    for (int off = 32; off > 0; off >>= 1) {
        unsigned long long o = __shfl_xor(key, off, 64);
        if (o > key) key = o;
    }
    return key;
}
#endif

// shared-memory arena (union of FPS and MLP layouts)
// FPS : xs[4096] ys[4096] zs[4096] (49152) | wred 2x4 u64 (64B) @49152
//       cbuf 2x24 f (192B) @49216 -> end 49408
// MLP : gbuf 32x68 (8704) @0 | hbuf 32x64 (8192) @8704 | pmax 8x128 (4096) @16896
//       cmask 64 u64 (512) @20992 | nbr 32 i (128) @21504
#define SMEM_BYTES 49664
#define WRED_OFF 49152
#define CBUF_OFF 49216

// R8 configuration — measured best (733 us). DO NOT pin registers and DO NOT
// pin waves_per_eu: R6 (pins+bounds: 840), R9 (pins+waves_per_eu(2,2): 781)
// both lost to letting the compiler rematerialize px/py/pz from GLOBAL
// (address-invariant loads, L1-resident, issued right after the barrier ->
// latency hides under the wred/gather LDS waits; effectively free prefetch).
__global__ __launch_bounds__(512, 2)
void fused_kernel(const float* __restrict__ xyz,
                  const float* __restrict__ points,
                  const float* __restrict__ w0, const float* __restrict__ b0,
                  const float* __restrict__ w1, const float* __restrict__ b1,
                  const float* __restrict__ w2, const float* __restrict__ b2,
                  float* __restrict__ out_xyz,
                  float* __restrict__ out_points,
                  int* __restrict__ ctr) {
    __shared__ __align__(16) char smem[SMEM_BYTES];
    const int tid = threadIdx.x;

    if (blockIdx.x < BB) {
        // ================= FPS (blocks 0..15, resident first => no deadlock) ====
        asm volatile("s_setprio 3");
        float* xs = (float*)smem;
        float* ys = xs + NN;
        float* zs = ys + NN;
        unsigned long long (*wred)[4] = (unsigned long long (*)[4])(smem + WRED_OFF);
        float (*cbuf)[24] = (float (*)[24])(smem + CBUF_OFF);   // double-buffered

        const int b = blockIdx.x;
        const float* __restrict__ xb = xyz + (size_t)b * (NN * 3);
        float* xo = out_xyz + (size_t)b * NPOINT * 3;

        if (tid < FPS_T) {
            // -------- compute waves 0..3: points from GLOBAL only (no LDS
            // alias for px/py/pz -> compiler remats from L1, which is free) --
            float px[PPT], py[PPT], pz[PPT], dist[PPT];
#pragma unroll
            for (int t = 0; t < PPT; ++t) {
                int p = tid + t * FPS_T;
                px[t] = xb[p * 3 + 0];
                py[t] = xb[p * 3 + 1];
                pz[t] = xb[p * 3 + 2];
                dist[t] = 1e10f;
            }
            __syncthreads();             // publisher waves staged xs/ys/zs

            const int lane = tid & 63, wid = tid >> 6;   // wid 0..3
            float cx = xs[0], cy = ys[0], cz = zs[0];

            for (int i = 0; i < NPOINT; ++i) {
                float bd = -1.0f; int bp = 0;
#pragma unroll
                for (int t = 0; t < PPT; ++t) {
                    float dx = __fsub_rn(px[t], cx);
                    float dy = __fsub_rn(py[t], cy);
                    float dz = __fsub_rn(pz[t], cz);
                    float d  = __fadd_rn(__fadd_rn(__fmul_rn(dx, dx), __fmul_rn(dy, dy)),
                                         __fmul_rn(dz, dz));
                    float nd = fminf(dist[t], d);
                    dist[t] = nd;
                    if (nd > bd) { bd = nd; bp = tid + t * FPS_T; }
                }
                unsigned long long key = (((unsigned long long)__float_as_uint(bd)) << 32)
                                       | (unsigned int)(NN - 1 - bp);
                key = wave_max_key(key);
                if (lane == 63) wred[i & 1][wid] = key;
                // stage centroid i into cbuf AFTER the sweep+reduce (was at
                // loop top): overlaps other waves' barrier arrival instead of
                // delaying wave 0's sweep start. Same cx/cy/cz values; still
                // strictly before the barrier wave 4 publishes after.
                if (tid == 0) {
                    float* cb = cbuf[(i >> 3) & 1];
                    cb[(i & 7) * 3 + 0] = cx;
                    cb[(i & 7) * 3 + 1] = cy;
                    cb[(i & 7) * 3 + 2] = cz;
                }
                __syncthreads();

                unsigned long long best = wred[i & 1][0];
#pragma unroll
                for (int w = 1; w < 4; ++w) {
                    unsigned long long o = wred[i & 1][w];
                    if (o > best) best = o;
                }
                int bi = (NN - 1) - (int)(best & 0xffffffffu);
                cx = xs[bi]; cy = ys[bi]; cz = zs[bi];
            }
        } else {
            // -------- waves 4..7: stage LDS coords, then barrier-matched publish
            {
                const int q = tid - FPS_T;     // 0..255
#pragma unroll
                for (int t = 0; t < PPT; ++t) {
                    int p = q + t * FPS_T;
                    xs[p] = xb[p * 3 + 0];
                    ys[p] = xb[p * 3 + 1];
                    zs[p] = xb[p * 3 + 2];
                }
            }
            __syncthreads();             // matches compute's post-load barrier

            for (int i = 0; i < NPOINT; ++i) {
                __syncthreads();         // matches compute's mid-iter barrier
                if (tid == FPS_T && (i & 7) == 7) {
                    // Pipelined publish: vmcnt(0) -> previous group's stores are
                    // done -> bump ctr for it; then issue this group's stores.
                    asm volatile("s_waitcnt vmcnt(0)" ::: "memory");
                    if (i > 7)
                        __hip_atomic_store(&ctr[b * 16], i - 7,
                                           __ATOMIC_RELAXED, __HIP_MEMORY_SCOPE_AGENT);
                    const unsigned long long* cbu =
                        (const unsigned long long*)cbuf[(i >> 3) & 1];
                    unsigned long long* dst =
                        (unsigned long long*)(xo + (size_t)(i - 7) * 3);
#pragma unroll
                    for (int q = 0; q < 12; ++q)
                        __hip_atomic_store(dst + q, cbu[q],
                                           __ATOMIC_RELAXED, __HIP_MEMORY_SCOPE_AGENT);
                }
            }
            if (tid == FPS_T) {          // final drain: last two groups visible
                asm volatile("s_waitcnt vmcnt(0)" ::: "memory");
                __hip_atomic_store(&ctr[b * 16], NPOINT,
                                   __ATOMIC_RELAXED, __HIP_MEMORY_SCOPE_AGENT);
            }
        }
    } else {
        // ================= fused ball query + gather + MLP + maxpool ===========
        // (R0/R2/R5-proven consumer: 1 centroid/block, s-major, relaxed protocol)
        float (*gbuf)[68] = (float (*)[68])smem;                 // 32 x (67+pad)
        float (*hbuf)[F1] = (float (*)[F1])(smem + 8704);        // 32 x 64
        float (*pmax)[F3] = (float (*)[F3])(smem + 16896);       // 8 x 128
        unsigned long long* cmask = (unsigned long long*)(smem + 20992);
        int* nbr = (int*)(smem + 21504);

        const int gi = blockIdx.x - BB;
        const int s = gi >> 4;          // s-major: early blocks need early centroids
        const int b = gi & 15;
        const int g = b * NPOINT + s;
        const int f = tid & 63;
        const int wid = tid >> 6;       // 0..7

        // wait until centroid s is published. No ACQUIRE: producer data is
        // sc1/LLC-coherent and centroid reads below are sc1 relaxed-atomic
        // loads; __syncthreads orders the block. (no buffer_inv)
        if (tid == 0) {
            while (__hip_atomic_load(&ctr[b * 16], __ATOMIC_RELAXED,
                                     __HIP_MEMORY_SCOPE_AGENT) < s + 1)
                __builtin_amdgcn_s_sleep(2);
        }
        __syncthreads();

        // centroid via agent-scope loads (LLC-direct; immune to stale per-XCD L2)
        unsigned int ux = __hip_atomic_load((unsigned int*)&out_xyz[(size_t)g * 3 + 0],
                                            __ATOMIC_RELAXED, __HIP_MEMORY_SCOPE_AGENT);
        unsigned int uy = __hip_atomic_load((unsigned int*)&out_xyz[(size_t)g * 3 + 1],
                                            __ATOMIC_RELAXED, __HIP_MEMORY_SCOPE_AGENT);
        unsigned int uz = __hip_atomic_load((unsigned int*)&out_xyz[(size_t)g * 3 + 2],
                                            __ATOMIC_RELAXED, __HIP_MEMORY_SCOPE_AGENT);
        const float cx = __uint_as_float(ux);
        const float cy = __uint_as_float(uy);
        const float cz = __uint_as_float(uz);

        // ---- phase A1: 8 waves scan all 4096 points ----
        {
            const float* __restrict__ xb = xyz + (size_t)b * (NN * 3);
#pragma unroll
            for (int j = 0; j < 8; ++j) {
                int chunk = wid * 8 + j;
                int p = chunk * 64 + f;
                float x = xb[p * 3 + 0];
                float y = xb[p * 3 + 1];
                float z = xb[p * 3 + 2];
                float dx = __fsub_rn(cx, x);
                float dy = __fsub_rn(cy, y);
                float dz = __fsub_rn(cz, z);
                float d2 = __fadd_rn(__fadd_rn(__fmul_rn(dx, dx), __fmul_rn(dy, dy)),
                                     __fmul_rn(dz, dz));
                unsigned long long m = __ballot(d2 <= 0.04f);  // float32(0.2*0.2)
                if (f == 0) cmask[chunk] = m;
            }
        }
        __syncthreads();

        // ---- phase A2: wave 0 — ordered compaction of the 32 smallest indices ----
        if (tid < 64) {
            unsigned long long m = cmask[tid];
            int cnt = (int)__popcll(m);
            int v = cnt;
#pragma unroll
            for (int off = 1; off < 64; off <<= 1) {
                int u = __shfl_up(v, off, 64);
                if (tid >= off) v += u;
            }
            int excl = v - cnt;
            int total = __shfl(v, 63, 64);
            unsigned long long mm = m;
            int r = excl;
            while (mm && r < KK) {
                int bpos = __ffsll(mm) - 1;
                mm &= mm - 1;
                nbr[r++] = tid * 64 + bpos;
            }
            if (total < KK) {
                unsigned long long nz = __ballot(cnt > 0);
                int fchunk = __ffsll(nz) - 1;
                unsigned long long fm = cmask[fchunk];
                int first = fchunk * 64 + __ffsll(fm) - 1;
                if (tid >= total && tid < KK) nbr[tid] = first;
            }
        }
        __syncthreads();

        // ---- phase B: gather into LDS ----
        {
            const float* __restrict__ pb = points + (size_t)b * NN * CC;
#pragma unroll
            for (int m = 0; m < 4; ++m) {
                int k = wid + 8 * m;
                int idx = nbr[k] & (NN - 1);
                gbuf[k][f] = pb[(size_t)idx * CC + f];
            }
            if (tid < 96) {
                int k = tid & 31, q = tid >> 5;
                int idx = nbr[k] & (NN - 1);
                float v = xyz[((size_t)b * NN + idx) * 3 + q];
                float cq = (q == 0) ? cx : ((q == 1) ? cy : cz);
                gbuf[k][CC + q] = __fsub_rn(v, cq);
            }
        }
        __syncthreads();

        float acc[4];

        // ---- layer 1: 67 -> 64 ----
#pragma unroll
        for (int m = 0; m < 4; ++m) acc[m] = 0.0f;
#pragma unroll 4
        for (int c4 = 0; c4 < 64; c4 += 4) {
            float wv0 = w0[(c4 + 0) * F1 + f];
            float wv1 = w0[(c4 + 1) * F1 + f];
            float wv2 = w0[(c4 + 2) * F1 + f];
            float wv3 = w0[(c4 + 3) * F1 + f];
#pragma unroll
            for (int m = 0; m < 4; ++m) {
                float4 gv = *(const float4*)&gbuf[wid + 8 * m][c4];
                acc[m] = fmaf(gv.x, wv0, acc[m]);
                acc[m] = fmaf(gv.y, wv1, acc[m]);
                acc[m] = fmaf(gv.z, wv2, acc[m]);
                acc[m] = fmaf(gv.w, wv3, acc[m]);
            }
        }
        {
            float wv0 = w0[64 * F1 + f];
            float wv1 = w0[65 * F1 + f];
            float wv2 = w0[66 * F1 + f];
#pragma unroll
            for (int m = 0; m < 4; ++m) {
                int k = wid + 8 * m;
                acc[m] = fmaf(gbuf[k][64], wv0, acc[m]);
                acc[m] = fmaf(gbuf[k][65], wv1, acc[m]);
                acc[m] = fmaf(gbuf[k][66], wv2, acc[m]);
            }
        }
        {
            float bb = b0[f];
#pragma unroll
            for (int m = 0; m < 4; ++m)
                hbuf[wid + 8 * m][f] = fmaxf(acc[m] + bb, 0.0f);
        }
        __syncthreads();

        // ---- layer 2: 64 -> 64 ----
#pragma unroll
        for (int m = 0; m < 4; ++m) acc[m] = 0.0f;
#pragma unroll 4
        for (int c4 = 0; c4 < 64; c4 += 4) {
            float wv0 = w1[(c4 + 0) * F2 + f];
            float wv1 = w1[(c4 + 1) * F2 + f];
            float wv2 = w1[(c4 + 2) * F2 + f];
            float wv3 = w1[(c4 + 3) * F2 + f];
#pragma unroll
            for (int m = 0; m < 4; ++m) {
                float4 gv = *(const float4*)&hbuf[wid + 8 * m][c4];
                acc[m] = fmaf(gv.x, wv0, acc[m]);
                acc[m] = fmaf(gv.y, wv1, acc[m]);
                acc[m] = fmaf(gv.z, wv2, acc[m]);
                acc[m] = fmaf(gv.w, wv3, acc[m]);
            }
        }
        {
            float bb = b1[f];
#pragma unroll
            for (int m = 0; m < 4; ++m)
                gbuf[wid + 8 * m][f] = fmaxf(acc[m] + bb, 0.0f);
        }
        __syncthreads();

        // ---- layer 3: 64 -> 128 + maxpool ----
        float a0[4], a1[4];
#pragma unroll
        for (int m = 0; m < 4; ++m) { a0[m] = 0.0f; a1[m] = 0.0f; }
#pragma unroll 2
        for (int c4 = 0; c4 < 64; c4 += 4) {
            float w00 = w2[(c4 + 0) * F3 + f], w10 = w2[(c4 + 0) * F3 + f + 64];
            float w01 = w2[(c4 + 1) * F3 + f], w11 = w2[(c4 + 1) * F3 + f + 64];
            float w02 = w2[(c4 + 2) * F3 + f], w12 = w2[(c4 + 2) * F3 + f + 64];
            float w03 = w2[(c4 + 3) * F3 + f], w13 = w2[(c4 + 3) * F3 + f + 64];
#pragma unroll
            for (int m = 0; m < 4; ++m) {
                float4 gv = *(const float4*)&gbuf[wid + 8 * m][c4];
                a0[m] = fmaf(gv.x, w00, a0[m]);  a1[m] = fmaf(gv.x, w10, a1[m]);
                a0[m] = fmaf(gv.y, w01, a0[m]);  a1[m] = fmaf(gv.y, w11, a1[m]);
                a0[m] = fmaf(gv.z, w02, a0[m]);  a1[m] = fmaf(gv.z, w12, a1[m]);
                a0[m] = fmaf(gv.w, w03, a0[m]);  a1[m] = fmaf(gv.w, w13, a1[m]);
            }
        }
        {
            float pm0 = -1e30f, pm1 = -1e30f;
#pragma unroll
            for (int m = 0; m < 4; ++m) {
                pm0 = fmaxf(pm0, a0[m]);
                pm1 = fmaxf(pm1, a1[m]);
            }
            pmax[wid][f] = pm0;
            pmax[wid][f + 64] = pm1;
        }
        __syncthreads();
        if (tid < F3) {
            float v = pmax[0][tid];
#pragma unroll
            for (int w = 1; w < 8; ++w) v = fmaxf(v, pmax[w][tid]);
            v = fmaxf(v + b2[tid], 0.0f);   // relu(max+b) == max(relu(+b))
            out_points[(size_t)g * F3 + tid] = v;
        }
    }
}

extern "C" void kernel_launch(void* const* d_in, const int* in_sizes, int n_in,
                              void* d_out, int out_size, void* d_ws, size_t ws_size,
                              hipStream_t stream) {
    const float* xyz    = (const float*)d_in[0];
    const float* points = (const float*)d_in[1];
    const float* w0 = (const float*)d_in[2];
    const float* b0 = (const float*)d_in[3];
    const float* w1 = (const float*)d_in[4];
    const float* b1 = (const float*)d_in[5];
    const float* w2 = (const float*)d_in[6];
    const float* b2 = (const float*)d_in[7];

    float* out_xyz    = (float*)d_out;
    float* out_points = out_xyz + (size_t)BB * NPOINT * 3;
    int*   ctr        = (int*)d_ws;   // 16 counters, 64B stride (1 KiB used)

    fused_kernel<<<BB + BB * NPOINT, 512, 0, stream>>>(
        xyz, points, w0, b0, w1, b1, w2, b2, out_xyz, out_points, ctr);
}

// Round 11
// 732.974 us; speedup vs baseline: 1.0659x; 1.0247x over previous
//
#include <hip/hip_runtime.h>
#include <stdint.h>

#define BB 16
#define NN 4096
#define CC 64
#define NPOINT 1024
#define KK 32
#define F1 64
#define F2 64
#define F3 128

#define FPS_T 256          // FPS compute threads: 4 waves (1 per SIMD)
#define PPT (NN / FPS_T)   // 16 points per thread

// ---------------- DPP 64-lane max-reduce helpers ----------------
#if defined(__has_builtin)
#if __has_builtin(__builtin_amdgcn_update_dpp)
#define HAS_DPP 1
#endif
#endif

#ifdef HAS_DPP
template <int CTRL>
__device__ __forceinline__ unsigned long long dpp_move64(unsigned long long k) {
    int lo = __builtin_amdgcn_update_dpp(0, (int)(unsigned)k,         CTRL, 0xF, 0xF, false);
    int hi = __builtin_amdgcn_update_dpp(0, (int)(unsigned)(k >> 32), CTRL, 0xF, 0xF, false);
    return ((unsigned long long)(unsigned)hi << 32) | (unsigned)lo;
}
__device__ __forceinline__ unsigned long long wave_max_key(unsigned long long key) {
    unsigned long long o;
    o = dpp_move64<0x111>(key); if (o > key) key = o;   // row_shr:1
    o = dpp_move64<0x112>(key); if (o > key) key = o;   // row_shr:2
    o = dpp_move64<0x114>(key); if (o > key) key = o;   // row_shr:4
    o = dpp_move64<0x118>(key); if (o > key) key = o;   // row_shr:8
    o = dpp_move64<0x142>(key); if (o > key) key = o;   // row_bcast15
    o = dpp_move64<0x143>(key); if (o > key) key = o;   // row_bcast31 -> lane63 has max
    return key;
}
#else
__device__ __forceinline__ unsigned long long wave_max_key(unsigned long long key) {
#pragma unroll
    for (int off = 32; off > 0; off >>= 1) {
        unsigned long long o = __shfl_xor(key, off, 64);
        if (o > key) key = o;
    }
    return key;
}
#endif

// shared-memory arena (union of FPS and MLP layouts)
// FPS : xs[4096] ys[4096] zs[4096] (49152) | wred 2x4 u64 (64B) @49152
//       cbuf 2x24 f (192B) @49216 -> end 49408
// MLP : gbuf 32x68 (8704) @0 | hbuf 32x64 (8192) @8704 | pmax 8x128 (4096) @16896
//       cmask 64 u64 (512) @20992 | nbr 32 i (128) @21504
#define SMEM_BYTES 49664
#define WRED_OFF 49152
#define CBUF_OFF 49216

// LOCKED BEST CONFIG (R8, 733 us). Session A/B ledger for this FPS loop:
//  - compute waves load points from GLOBAL ONLY; compiler remats px/py/pz
//    from L1 each iteration (VGPR=60). FORCING register residency loses:
//    R6 pins+bounds 840us (scratch spill), R9 pins+waves_per_eu(2,2) 781us
//    (halved chip occupancy). The remat loads are address-invariant,
//    L1-resident, issued right after the barrier -> effectively free prefetch.
//  - cbuf centroid staging at LOOP TOP (R10 moved it post-reduce: 751us).
//  - wred 2x4 array + 4-entry scan (R7 key+coord tournament: 780us;
//    R6 ds_max_rtn single-slot: 840us).
//  - 4 compute waves, 1/SIMD (R0/R2 8-wave: 815-860us).
//  - publisher wave 4 does all global stores + ctr bumps off-path, relaxed
//    agent-scope (sc1) protocol, pipelined vmcnt drain.
__global__ __launch_bounds__(512, 2)
void fused_kernel(const float* __restrict__ xyz,
                  const float* __restrict__ points,
                  const float* __restrict__ w0, const float* __restrict__ b0,
                  const float* __restrict__ w1, const float* __restrict__ b1,
                  const float* __restrict__ w2, const float* __restrict__ b2,
                  float* __restrict__ out_xyz,
                  float* __restrict__ out_points,
                  int* __restrict__ ctr) {
    __shared__ __align__(16) char smem[SMEM_BYTES];
    const int tid = threadIdx.x;

    if (blockIdx.x < BB) {
        // ================= FPS (blocks 0..15, resident first => no deadlock) ====
        asm volatile("s_setprio 3");
        float* xs = (float*)smem;
        float* ys = xs + NN;
        float* zs = ys + NN;
        unsigned long long (*wred)[4] = (unsigned long long (*)[4])(smem + WRED_OFF);
        float (*cbuf)[24] = (float (*)[24])(smem + CBUF_OFF);   // double-buffered

        const int b = blockIdx.x;
        const float* __restrict__ xb = xyz + (size_t)b * (NN * 3);
        float* xo = out_xyz + (size_t)b * NPOINT * 3;

        if (tid < FPS_T) {
            // -------- compute waves 0..3: points from GLOBAL only (no LDS
            // alias for px/py/pz -> compiler remats from L1, which is free) --
            float px[PPT], py[PPT], pz[PPT], dist[PPT];
#pragma unroll
            for (int t = 0; t < PPT; ++t) {
                int p = tid + t * FPS_T;
                px[t] = xb[p * 3 + 0];
                py[t] = xb[p * 3 + 1];
                pz[t] = xb[p * 3 + 2];
                dist[t] = 1e10f;
            }
            __syncthreads();             // publisher waves staged xs/ys/zs

            const int lane = tid & 63, wid = tid >> 6;   // wid 0..3
            float cx = xs[0], cy = ys[0], cz = zs[0];

            for (int i = 0; i < NPOINT; ++i) {
                if (tid == 0) {          // stage centroid i into LDS (cheap)
                    float* cb = cbuf[(i >> 3) & 1];
                    cb[(i & 7) * 3 + 0] = cx;
                    cb[(i & 7) * 3 + 1] = cy;
                    cb[(i & 7) * 3 + 2] = cz;
                }
                float bd = -1.0f; int bp = 0;
#pragma unroll
                for (int t = 0; t < PPT; ++t) {
                    float dx = __fsub_rn(px[t], cx);
                    float dy = __fsub_rn(py[t], cy);
                    float dz = __fsub_rn(pz[t], cz);
                    float d  = __fadd_rn(__fadd_rn(__fmul_rn(dx, dx), __fmul_rn(dy, dy)),
                                         __fmul_rn(dz, dz));
                    float nd = fminf(dist[t], d);
                    dist[t] = nd;
                    if (nd > bd) { bd = nd; bp = tid + t * FPS_T; }
                }
                unsigned long long key = (((unsigned long long)__float_as_uint(bd)) << 32)
                                       | (unsigned int)(NN - 1 - bp);
                key = wave_max_key(key);
                if (lane == 63) wred[i & 1][wid] = key;
                __syncthreads();

                unsigned long long best = wred[i & 1][0];
#pragma unroll
                for (int w = 1; w < 4; ++w) {
                    unsigned long long o = wred[i & 1][w];
                    if (o > best) best = o;
                }
                int bi = (NN - 1) - (int)(best & 0xffffffffu);
                cx = xs[bi]; cy = ys[bi]; cz = zs[bi];
            }
        } else {
            // -------- waves 4..7: stage LDS coords, then barrier-matched publish
            {
                const int q = tid - FPS_T;     // 0..255
#pragma unroll
                for (int t = 0; t < PPT; ++t) {
                    int p = q + t * FPS_T;
                    xs[p] = xb[p * 3 + 0];
                    ys[p] = xb[p * 3 + 1];
                    zs[p] = xb[p * 3 + 2];
                }
            }
            __syncthreads();             // matches compute's post-load barrier

            for (int i = 0; i < NPOINT; ++i) {
                __syncthreads();         // matches compute's mid-iter barrier
                if (tid == FPS_T && (i & 7) == 7) {
                    // Pipelined publish: vmcnt(0) -> previous group's stores are
                    // done -> bump ctr for it; then issue this group's stores.
                    asm volatile("s_waitcnt vmcnt(0)" ::: "memory");
                    if (i > 7)
                        __hip_atomic_store(&ctr[b * 16], i - 7,
                                           __ATOMIC_RELAXED, __HIP_MEMORY_SCOPE_AGENT);
                    const unsigned long long* cbu =
                        (const unsigned long long*)cbuf[(i >> 3) & 1];
                    unsigned long long* dst =
                        (unsigned long long*)(xo + (size_t)(i - 7) * 3);
#pragma unroll
                    for (int q = 0; q < 12; ++q)
                        __hip_atomic_store(dst + q, cbu[q],
                                           __ATOMIC_RELAXED, __HIP_MEMORY_SCOPE_AGENT);
                }
            }
            if (tid == FPS_T) {          // final drain: last two groups visible
                asm volatile("s_waitcnt vmcnt(0)" ::: "memory");
                __hip_atomic_store(&ctr[b * 16], NPOINT,
                                   __ATOMIC_RELAXED, __HIP_MEMORY_SCOPE_AGENT);
            }
        }
    } else {
        // ================= fused ball query + gather + MLP + maxpool ===========
        // (R0/R2/R5-proven consumer: 1 centroid/block, s-major, relaxed protocol)
        float (*gbuf)[68] = (float (*)[68])smem;                 // 32 x (67+pad)
        float (*hbuf)[F1] = (float (*)[F1])(smem + 8704);        // 32 x 64
        float (*pmax)[F3] = (float (*)[F3])(smem + 16896);       // 8 x 128
        unsigned long long* cmask = (unsigned long long*)(smem + 20992);
        int* nbr = (int*)(smem + 21504);

        const int gi = blockIdx.x - BB;
        const int s = gi >> 4;          // s-major: early blocks need early centroids
        const int b = gi & 15;
        const int g = b * NPOINT + s;
        const int f = tid & 63;
        const int wid = tid >> 6;       // 0..7

        // wait until centroid s is published. No ACQUIRE: producer data is
        // sc1/LLC-coherent and centroid reads below are sc1 relaxed-atomic
        // loads; __syncthreads orders the block. (no buffer_inv)
        if (tid == 0) {
            while (__hip_atomic_load(&ctr[b * 16], __ATOMIC_RELAXED,
                                     __HIP_MEMORY_SCOPE_AGENT) < s + 1)
                __builtin_amdgcn_s_sleep(2);
        }
        __syncthreads();

        // centroid via agent-scope loads (LLC-direct; immune to stale per-XCD L2)
        unsigned int ux = __hip_atomic_load((unsigned int*)&out_xyz[(size_t)g * 3 + 0],
                                            __ATOMIC_RELAXED, __HIP_MEMORY_SCOPE_AGENT);
        unsigned int uy = __hip_atomic_load((unsigned int*)&out_xyz[(size_t)g * 3 + 1],
                                            __ATOMIC_RELAXED, __HIP_MEMORY_SCOPE_AGENT);
        unsigned int uz = __hip_atomic_load((unsigned int*)&out_xyz[(size_t)g * 3 + 2],
                                            __ATOMIC_RELAXED, __HIP_MEMORY_SCOPE_AGENT);
        const float cx = __uint_as_float(ux);
        const float cy = __uint_as_float(uy);
        const float cz = __uint_as_float(uz);

        // ---- phase A1: 8 waves scan all 4096 points ----
        {
            const float* __restrict__ xb = xyz + (size_t)b * (NN * 3);
#pragma unroll
            for (int j = 0; j < 8; ++j) {
                int chunk = wid * 8 + j;
                int p = chunk * 64 + f;
                float x = xb[p * 3 + 0];
                float y = xb[p * 3 + 1];
                float z = xb[p * 3 + 2];
                float dx = __fsub_rn(cx, x);
                float dy = __fsub_rn(cy, y);
                float dz = __fsub_rn(cz, z);
                float d2 = __fadd_rn(__fadd_rn(__fmul_rn(dx, dx), __fmul_rn(dy, dy)),
                                     __fmul_rn(dz, dz));
                unsigned long long m = __ballot(d2 <= 0.04f);  // float32(0.2*0.2)
                if (f == 0) cmask[chunk] = m;
            }
        }
        __syncthreads();

        // ---- phase A2: wave 0 — ordered compaction of the 32 smallest indices ----
        if (tid < 64) {
            unsigned long long m = cmask[tid];
            int cnt = (int)__popcll(m);
            int v = cnt;
#pragma unroll
            for (int off = 1; off < 64; off <<= 1) {
                int u = __shfl_up(v, off, 64);
                if (tid >= off) v += u;
            }
            int excl = v - cnt;
            int total = __shfl(v, 63, 64);
            unsigned long long mm = m;
            int r = excl;
            while (mm && r < KK) {
                int bpos = __ffsll(mm) - 1;
                mm &= mm - 1;
                nbr[r++] = tid * 64 + bpos;
            }
            if (total < KK) {
                unsigned long long nz = __ballot(cnt > 0);
                int fchunk = __ffsll(nz) - 1;
                unsigned long long fm = cmask[fchunk];
                int first = fchunk * 64 + __ffsll(fm) - 1;
                if (tid >= total && tid < KK) nbr[tid] = first;
            }
        }
        __syncthreads();

        // ---- phase B: gather into LDS ----
        {
            const float* __restrict__ pb = points + (size_t)b * NN * CC;
#pragma unroll
            for (int m = 0; m < 4; ++m) {
                int k = wid + 8 * m;
                int idx = nbr[k] & (NN - 1);
                gbuf[k][f] = pb[(size_t)idx * CC + f];
            }
            if (tid < 96) {
                int k = tid & 31, q = tid >> 5;
                int idx = nbr[k] & (NN - 1);
                float v = xyz[((size_t)b * NN + idx) * 3 + q];
                float cq = (q == 0) ? cx : ((q == 1) ? cy : cz);
                gbuf[k][CC + q] = __fsub_rn(v, cq);
            }
        }
        __syncthreads();

        float acc[4];

        // ---- layer 1: 67 -> 64 ----
#pragma unroll
        for (int m = 0; m < 4; ++m) acc[m] = 0.0f;
#pragma unroll 4
        for (int c4 = 0; c4 < 64; c4 += 4) {
            float wv0 = w0[(c4 + 0) * F1 + f];
            float wv1 = w0[(c4 + 1) * F1 + f];
            float wv2 = w0[(c4 + 2) * F1 + f];
            float wv3 = w0[(c4 + 3) * F1 + f];
#pragma unroll
            for (int m = 0; m < 4; ++m) {
                float4 gv = *(const float4*)&gbuf[wid + 8 * m][c4];
                acc[m] = fmaf(gv.x, wv0, acc[m]);
                acc[m] = fmaf(gv.y, wv1, acc[m]);
                acc[m] = fmaf(gv.z, wv2, acc[m]);
                acc[m] = fmaf(gv.w, wv3, acc[m]);
            }
        }
        {
            float wv0 = w0[64 * F1 + f];
            float wv1 = w0[65 * F1 + f];
            float wv2 = w0[66 * F1 + f];
#pragma unroll
            for (int m = 0; m < 4; ++m) {
                int k = wid + 8 * m;
                acc[m] = fmaf(gbuf[k][64], wv0, acc[m]);
                acc[m] = fmaf(gbuf[k][65], wv1, acc[m]);
                acc[m] = fmaf(gbuf[k][66], wv2, acc[m]);
            }
        }
        {
            float bb = b0[f];
#pragma unroll
            for (int m = 0; m < 4; ++m)
                hbuf[wid + 8 * m][f] = fmaxf(acc[m] + bb, 0.0f);
        }
        __syncthreads();

        // ---- layer 2: 64 -> 64 ----
#pragma unroll
        for (int m = 0; m < 4; ++m) acc[m] = 0.0f;
#pragma unroll 4
        for (int c4 = 0; c4 < 64; c4 += 4) {
            float wv0 = w1[(c4 + 0) * F2 + f];
            float wv1 = w1[(c4 + 1) * F2 + f];
            float wv2 = w1[(c4 + 2) * F2 + f];
            float wv3 = w1[(c4 + 3) * F2 + f];
#pragma unroll
            for (int m = 0; m < 4; ++m) {
                float4 gv = *(const float4*)&hbuf[wid + 8 * m][c4];
                acc[m] = fmaf(gv.x, wv0, acc[m]);
                acc[m] = fmaf(gv.y, wv1, acc[m]);
                acc[m] = fmaf(gv.z, wv2, acc[m]);
                acc[m] = fmaf(gv.w, wv3, acc[m]);
            }
        }
        {
            float bb = b1[f];
#pragma unroll
            for (int m = 0; m < 4; ++m)
                gbuf[wid + 8 * m][f] = fmaxf(acc[m] + bb, 0.0f);
        }
        __syncthreads();

        // ---- layer 3: 64 -> 128 + maxpool ----
        float a0[4], a1[4];
#pragma unroll
        for (int m = 0; m < 4; ++m) { a0[m] = 0.0f; a1[m] = 0.0f; }
#pragma unroll 2
        for (int c4 = 0; c4 < 64; c4 += 4) {
            float w00 = w2[(c4 + 0) * F3 + f], w10 = w2[(c4 + 0) * F3 + f + 64];
            float w01 = w2[(c4 + 1) * F3 + f], w11 = w2[(c4 + 1) * F3 + f + 64];
            float w02 = w2[(c4 + 2) * F3 + f], w12 = w2[(c4 + 2) * F3 + f + 64];
            float w03 = w2[(c4 + 3) * F3 + f], w13 = w2[(c4 + 3) * F3 + f + 64];
#pragma unroll
            for (int m = 0; m < 4; ++m) {
                float4 gv = *(const float4*)&gbuf[wid + 8 * m][c4];
                a0[m] = fmaf(gv.x, w00, a0[m]);  a1[m] = fmaf(gv.x, w10, a1[m]);
                a0[m] = fmaf(gv.y, w01, a0[m]);  a1[m] = fmaf(gv.y, w11, a1[m]);
                a0[m] = fmaf(gv.z, w02, a0[m]);  a1[m] = fmaf(gv.z, w12, a1[m]);
                a0[m] = fmaf(gv.w, w03, a0[m]);  a1[m] = fmaf(gv.w, w13, a1[m]);
            }
        }
        {
            float pm0 = -1e30f, pm1 = -1e30f;
#pragma unroll
            for (int m = 0; m < 4; ++m) {
                pm0 = fmaxf(pm0, a0[m]);
                pm1 = fmaxf(pm1, a1[m]);
            }
            pmax[wid][f] = pm0;
            pmax[wid][f + 64] = pm1;
        }
        __syncthreads();
        if (tid < F3) {
            float v = pmax[0][tid];
#pragma unroll
            for (int w = 1; w < 8; ++w) v = fmaxf(v, pmax[w][tid]);
            v = fmaxf(v + b2[tid], 0.0f);   // relu(max+b) == max(relu(+b))
            out_points[(size_t)g * F3 + tid] = v;
        }
    }
}

extern "C" void kernel_launch(void* const* d_in, const int* in_sizes, int n_in,
                              void* d_out, int out_size, void* d_ws, size_t ws_size,
                              hipStream_t stream) {
    const float* xyz    = (const float*)d_in[0];
    const float* points = (const float*)d_in[1];
    const float* w0 = (const float*)d_in[2];
    const float* b0 = (const float*)d_in[3];
    const float* w1 = (const float*)d_in[4];
    const float* b1 = (const float*)d_in[5];
    const float* w2 = (const float*)d_in[6];
    const float* b2 = (const float*)d_in[7];

    float* out_xyz    = (float*)d_out;
    float* out_points = out_xyz + (size_t)BB * NPOINT * 3;
    int*   ctr        = (int*)d_ws;   // 16 counters, 64B stride (1 KiB used)

    fused_kernel<<<BB + BB * NPOINT, 512, 0, stream>>>(
        xyz, points, w0, b0, w1, b1, w2, b2, out_xyz, out_points, ctr);
}